// Round 4
// baseline (219.665 us; speedup 1.0000x reference)
//
#include <hip/hip_runtime.h>
#include <math.h>

// Problem: output [B=2, C=8, H=128, W=128, D=128] fp32.
// t = (x > 0.5 ? x : 0); per (b,c): s = sum t, sy = sum t*(y/H), sx = sum t*(x/W),
// sz = sum t*(z/D); centroids = weighted / s; 8 relations -> scalar loss.
// Memory-bound: 134 MB single-pass read -> ~21 us floor @ 6.3 TB/s.
//
// R4 = R3 with the compile fix: __builtin_nontemporal_load requires a native
// vector type, not HIP_vector_type -> use ext_vector_type(4) float.

#define SLICES 16
#define SLICE_ELEMS (128*128*128)
#define BLOCKS_PER_SLICE 64
#define THREADS 256
#define NBLOCKS (SLICES * BLOCKS_PER_SLICE)    // 1024
#define STRIDE (BLOCKS_PER_SLICE * THREADS)    // 16384 -> exactly 32 iters/thread
#define FLAG_MAGIC 0x13579BDFu

typedef float floatx4 __attribute__((ext_vector_type(4)));

// ws layout (floats): [0..1023]=s, [1024..2047]=sy, [2048..3071]=sx,
// [3072..4095]=sz, then 1024 u32 flags at [4096..5119]. slot = slice*64+blk.

__global__ __launch_bounds__(THREADS)
void gsl_fused(const float* __restrict__ in, float* __restrict__ ws,
               float* __restrict__ out) {
    const int blk   = blockIdx.x;      // 0..63
    const int slice = blockIdx.y;      // 0..15
    const int slot  = slice * BLOCKS_PER_SLICE + blk;
    const int tid   = threadIdx.x;

    unsigned int* flags = reinterpret_cast<unsigned int*>(ws + 4 * NBLOCKS);

    const floatx4* p = reinterpret_cast<const floatx4*>(in + (size_t)slice * SLICE_ELEMS);
    const int base = blk * THREADS + tid;

    float s = 0.0f, sy = 0.0f, sx = 0.0f, sz = 0.0f;

    #pragma unroll 8
    for (int i = 0; i < 32; ++i) {
        const int v = base + i * STRIDE;
        floatx4 f = __builtin_nontemporal_load(&p[v]);
        const int e = v << 2;                      // element index of f.x
        float t0 = f.x > 0.5f ? f.x : 0.0f;
        float t1 = f.y > 0.5f ? f.y : 0.0f;
        float t2 = f.z > 0.5f ? f.z : 0.0f;
        float t3 = f.w > 0.5f ? f.w : 0.0f;
        float ts = (t0 + t1) + (t2 + t3);
        float zz = (float)(e & 127);               // z fastest
        float xx = (float)((e >> 7) & 127);
        float yy = (float)(e >> 14);
        s  += ts;
        sy += ts * yy;
        sx += ts * xx;
        sz += ts * zz + (t1 + 2.0f * t2 + 3.0f * t3);
    }

    const float inv = 1.0f / 128.0f;               // H=W=D=128
    sy *= inv; sx *= inv; sz *= inv;

    #pragma unroll
    for (int off = 32; off > 0; off >>= 1) {
        s  += __shfl_down(s,  off, 64);
        sy += __shfl_down(sy, off, 64);
        sx += __shfl_down(sx, off, 64);
        sz += __shfl_down(sz, off, 64);
    }

    __shared__ float4 sh[4];
    const int wave = tid >> 6;
    const int lane = tid & 63;
    if (lane == 0) sh[wave] = make_float4(s, sy, sx, sz);
    __syncthreads();

    if (tid == 0) {
        float4 a = sh[0], b = sh[1], c = sh[2], d = sh[3];
        float ps  = (a.x + b.x) + (c.x + d.x);
        float psy = (a.y + b.y) + (c.y + d.y);
        float psx = (a.z + b.z) + (c.z + d.z);
        float psz = (a.w + b.w) + (c.w + d.w);
        // publish through device-coherent atomics (ws is poison-filled, and
        // per-XCD L2s are not cross-coherent for plain stores)
        atomicExch(&ws[0 * NBLOCKS + slot], ps);
        atomicExch(&ws[1 * NBLOCKS + slot], psy);
        atomicExch(&ws[2 * NBLOCKS + slot], psx);
        atomicExch(&ws[3 * NBLOCKS + slot], psz);
        __threadfence();
        atomicExch(&flags[slot], FLAG_MAGIC);
    }

    // ---- fused finalize: last block spins, then reduces 1024 partials ----
    if (blk != BLOCKS_PER_SLICE - 1 || slice != SLICES - 1) return;

    // each of 256 threads polls 4 flags
    {
        bool done = false;
        while (!done) {
            done = true;
            #pragma unroll
            for (int i = 0; i < 4; ++i) {
                if (atomicAdd(&flags[tid * 4 + i], 0u) != FLAG_MAGIC) { done = false; }
            }
        }
    }
    __threadfence();
    __syncthreads();

    // thread t: slice fs = t>>4, covers 4 consecutive partial slots
    const int fs = tid >> 4;
    const int chunk = tid & 15;
    float rs = 0.0f, rsy = 0.0f, rsx = 0.0f, rsz = 0.0f;
    #pragma unroll
    for (int i = 0; i < 4; ++i) {
        const int sl = fs * BLOCKS_PER_SLICE + chunk * 4 + i;
        rs  += atomicAdd(&ws[0 * NBLOCKS + sl], 0.0f);
        rsy += atomicAdd(&ws[1 * NBLOCKS + sl], 0.0f);
        rsx += atomicAdd(&ws[2 * NBLOCKS + sl], 0.0f);
        rsz += atomicAdd(&ws[3 * NBLOCKS + sl], 0.0f);
    }
    #pragma unroll
    for (int off = 8; off > 0; off >>= 1) {
        rs  += __shfl_down(rs,  off, 16);
        rsy += __shfl_down(rsy, off, 16);
        rsx += __shfl_down(rsx, off, 16);
        rsz += __shfl_down(rsz, off, 16);
    }

    __shared__ float cy[SLICES], cx[SLICES], cz[SLICES];
    if (chunk == 0) {
        cy[fs] = rsy / rs;
        cx[fs] = rsx / rs;
        cz[fs] = rsz / rs;
    }
    __syncthreads();

    if (tid == 0) {
        const int   ri[8] = {0, 1, 2, 3, 4, 5, 6, 0};
        const int   rj[8] = {1, 2, 3, 4, 5, 6, 7, 7};
        const float gy[8] = { 0.1f, 0.0f, -0.1f, 0.0f,  0.05f, 0.0f, 0.1f, -0.05f};
        const float gx[8] = { 0.0f, 0.1f,  0.05f, 0.0f, -0.05f, 0.1f, 0.0f,  0.05f};
        const float gz[8] = { 0.05f, 0.0f, 0.0f,  0.1f,  0.0f, -0.1f, 0.0f,  0.05f};

        float loss = 0.0f;
        #pragma unroll
        for (int r = 0; r < 8; ++r) {
            #pragma unroll
            for (int b = 0; b < 2; ++b) {
                int i = b * 8 + ri[r];
                int j = b * 8 + rj[r];
                float dy = cy[i] - cy[j] - gy[r];
                float dx = cx[i] - cx[j] - gx[r];
                float dz = cz[i] - cz[j] - gz[r];
                if (!isfinite(dy)) dy = 0.0f;
                if (!isfinite(dx)) dx = 0.0f;
                if (!isfinite(dz)) dz = 0.0f;
                loss += 0.5f * (dy * dy + dx * dx + dz * dz);  // mean over B=2
            }
        }
        out[0] = loss;
    }
}

extern "C" void kernel_launch(void* const* d_in, const int* in_sizes, int n_in,
                              void* d_out, int out_size, void* d_ws, size_t ws_size,
                              hipStream_t stream) {
    const float* in = (const float*)d_in[0];
    float* out = (float*)d_out;
    float* ws = (float*)d_ws;   // 4*1024 floats partials + 1024 u32 flags

    gsl_fused<<<dim3(BLOCKS_PER_SLICE, SLICES), THREADS, 0, stream>>>(in, ws, out);
}